// Round 1
// baseline (232.759 us; speedup 1.0000x reference)
//
#include <hip/hip_runtime.h>

// Compact Bilinear Pooling, restructured:
//   out[b,d] = sum_{c1,c2 : (h1[c1]+h2[c2]) & 8191 == d} s1[c1]*s2[c2]*G[b,c1,c2]
//   G[b,c1,c2] = sum_{p<196} bottom1[b,c1,p] * bottom2[b,c2,p]
// No FFT needed: circular conv of two count-sketches is a scatter of the
// pixel-summed outer product G.

#define D     8192
#define DMASK 8191
#define C     512
#define HW    196     // 14*14, contiguous innermost in [B,C,H,W]
#define NB    32

// ---------------------------------------------------------------------------
// Phase 1: recover (h[c], s[c]) from the dense sketch matrix S[512][8192]
// (exactly one nonzero +-1 per row). One block per row, float4 scan.
// ---------------------------------------------------------------------------
__global__ __launch_bounds__(256) void extract_sketch(
    const float* __restrict__ S, int* __restrict__ h, float* __restrict__ s)
{
    const int row = blockIdx.x;
    const float4* rp = (const float4*)(S + (size_t)row * D);
    for (int i = threadIdx.x; i < D / 4; i += 256) {
        float4 v = rp[i];
        if (v.x != 0.f) { h[row] = 4 * i + 0; s[row] = v.x; }
        if (v.y != 0.f) { h[row] = 4 * i + 1; s[row] = v.y; }
        if (v.z != 0.f) { h[row] = 4 * i + 2; s[row] = v.z; }
        if (v.w != 0.f) { h[row] = 4 * i + 3; s[row] = v.w; }
    }
}

// ---------------------------------------------------------------------------
// Phase 2: fused GEMM(128x128 tile, K=196) + scatter into LDS histogram,
// then one coalesced global-atomic flush per block.
// Grid: (xc2=2, t1=4, b=32) = 256 blocks, 256 threads.
// Thread tile 8x8; s1 folded into A-tile, s2 into B-tile at staging time.
// ---------------------------------------------------------------------------
__global__ __launch_bounds__(256) void cbp_fused(
    const float* __restrict__ b1, const float* __restrict__ b2,
    const int* __restrict__ h1, const float* __restrict__ s1,
    const int* __restrict__ h2, const float* __restrict__ s2,
    float* __restrict__ out)
{
    const int b   = blockIdx.z;
    const int t1  = blockIdx.y;   // c1 tile: [t1*128, t1*128+128)
    const int xc2 = blockIdx.x;   // c2 half: [xc2*256, xc2*256+256)

    __shared__ float hist[D];          // 32 KB output histogram
    __shared__ float As[16][128];      // k-major A chunk (c1 dim inner)
    __shared__ float Bs[16][128];      // k-major B chunk (c2 dim inner)
    __shared__ int   h1t[128];
    __shared__ float s1t[128];
    __shared__ int   h2t[C];
    __shared__ float s2t[C];

    const int tid = threadIdx.x;
    const int tx = tid & 15;           // c2 micro index
    const int ty = tid >> 4;           // c1 micro index

    for (int i = tid; i < D; i += 256) hist[i] = 0.f;
    if (tid < 128) {
        h1t[tid] = h1[t1 * 128 + tid];
        s1t[tid] = s1[t1 * 128 + tid];
    }
    for (int i = tid; i < C; i += 256) {
        h2t[i] = h2[i];
        s2t[i] = s2[i];
    }
    __syncthreads();

    const float* Abase  = b1 + ((size_t)b * C + (size_t)t1 * 128) * HW;
    const float* Bbase0 = b2 + (size_t)b * C * HW;

    // staging mapping: 128 rows x 16 k per chunk = 2048 floats, 8 per thread
    const int r  = tid >> 1;           // row 0..127
    const int cg = (tid & 1) * 8;      // k col group {0,8}

    const float sa = s1t[r];

    for (int c2c = 0; c2c < 2; ++c2c) {
        const int c2g = xc2 * 256 + c2c * 128;    // global c2 base of chunk
        const float* Bbase = Bbase0 + (size_t)c2g * HW;
        const float sb = s2t[c2g + r];

        float acc[8][8];
        #pragma unroll
        for (int i = 0; i < 8; ++i)
            #pragma unroll
            for (int j = 0; j < 8; ++j) acc[i][j] = 0.f;

        for (int k0 = 0; k0 < HW; k0 += 16) {
            __syncthreads();   // previous chunk's reads done before overwrite
            {
                const int gk = k0 + cg;
                const float* pa = Abase + (size_t)r * HW + gk;
                const float* pb = Bbase + (size_t)r * HW + gk;
                const float4 z = {0.f, 0.f, 0.f, 0.f};
                float4 a0 = (gk + 4 <= HW) ? *(const float4*)pa       : z;
                float4 a1 = (gk + 8 <= HW) ? *(const float4*)(pa + 4) : z;
                float4 q0 = (gk + 4 <= HW) ? *(const float4*)pb       : z;
                float4 q1 = (gk + 8 <= HW) ? *(const float4*)(pb + 4) : z;
                As[cg + 0][r] = sa * a0.x;  As[cg + 1][r] = sa * a0.y;
                As[cg + 2][r] = sa * a0.z;  As[cg + 3][r] = sa * a0.w;
                As[cg + 4][r] = sa * a1.x;  As[cg + 5][r] = sa * a1.y;
                As[cg + 6][r] = sa * a1.z;  As[cg + 7][r] = sa * a1.w;
                Bs[cg + 0][r] = sb * q0.x;  Bs[cg + 1][r] = sb * q0.y;
                Bs[cg + 2][r] = sb * q0.z;  Bs[cg + 3][r] = sb * q0.w;
                Bs[cg + 4][r] = sb * q1.x;  Bs[cg + 5][r] = sb * q1.y;
                Bs[cg + 6][r] = sb * q1.z;  Bs[cg + 7][r] = sb * q1.w;
            }
            __syncthreads();
            #pragma unroll
            for (int k = 0; k < 16; ++k) {
                float av[8], bv[8];
                #pragma unroll
                for (int i = 0; i < 8; ++i) av[i] = As[k][ty * 8 + i];
                #pragma unroll
                for (int j = 0; j < 8; ++j) bv[j] = Bs[k][tx * 8 + j];
                #pragma unroll
                for (int i = 0; i < 8; ++i)
                    #pragma unroll
                    for (int j = 0; j < 8; ++j)
                        acc[i][j] += av[i] * bv[j];
            }
        }

        // scatter this 128x128 tile of weighted G into the LDS histogram
        int p1[8], p2[8];
        #pragma unroll
        for (int i = 0; i < 8; ++i) p1[i] = h1t[ty * 8 + i];
        #pragma unroll
        for (int j = 0; j < 8; ++j) p2[j] = h2t[c2g + tx * 8 + j];
        #pragma unroll
        for (int i = 0; i < 8; ++i)
            #pragma unroll
            for (int j = 0; j < 8; ++j)
                atomicAdd(&hist[(p1[i] + p2[j]) & DMASK], acc[i][j]);
    }

    __syncthreads();
    float* orow = out + (size_t)b * D;
    for (int i = tid; i < D; i += 256)
        atomicAdd(&orow[i], hist[i]);
}

// ---------------------------------------------------------------------------
extern "C" void kernel_launch(void* const* d_in, const int* in_sizes, int n_in,
                              void* d_out, int out_size, void* d_ws, size_t ws_size,
                              hipStream_t stream)
{
    const float* bottom1 = (const float*)d_in[0];
    const float* bottom2 = (const float*)d_in[1];
    const float* S1      = (const float*)d_in[2];
    const float* S2      = (const float*)d_in[3];
    float* out = (float*)d_out;

    int*   h1 = (int*)d_ws;
    int*   h2 = h1 + C;
    float* s1 = (float*)(h2 + C);
    float* s2 = s1 + C;

    hipMemsetAsync(d_out, 0, sizeof(float) * NB * D, stream);
    extract_sketch<<<C, 256, 0, stream>>>(S1, h1, s1);
    extract_sketch<<<C, 256, 0, stream>>>(S2, h2, s2);
    cbp_fused<<<dim3(2, 4, NB), 256, 0, stream>>>(bottom1, bottom2,
                                                  h1, s1, h2, s2, out);
}

// Round 2
// 158.186 us; speedup vs baseline: 1.4714x; 1.4714x over previous
//
#include <hip/hip_runtime.h>

// Compact Bilinear Pooling via count-sketch algebra (no FFT):
//   out[b,d] = sum_{c1,c2 : (h1[c1]+h2[c2]) & 8191 == d} s1[c1]*s2[c2]*G[b,c1,c2]
//   G[b,c1,c2] = sum_{p<196} bottom1[b,c1,p] * bottom2[b,c2,p]
// G computed with bf16 MFMA (threshold 7.52 allows it; s=+-1 folded as exact
// sign flips at staging), scattered into a per-block LDS histogram.

#define D     8192
#define DMASK 8191
#define C     512
#define HW    196     // 14*14, contiguous innermost
#define NB    32
#define LDK   40      // bf16 elements per LDS row: 32 data + 8 pad
                      // stride 80B -> 16 frag-read lanes cover all 32 banks 2x (free)
#define NCH   7       // ceil(196/32), tail zero-padded

typedef __attribute__((ext_vector_type(8))) short bf16x8;
typedef __attribute__((ext_vector_type(4))) float f32x4;

// fp32 -> bf16 RNE with sign-mask fold (s = +-1 -> exact xor of sign bit)
__device__ __forceinline__ unsigned short f2bf(float f, unsigned xm) {
    unsigned u = __float_as_uint(f) ^ xm;
    return (unsigned short)((u + 0x7fffu + ((u >> 16) & 1u)) >> 16);
}

// ---------------------------------------------------------------------------
// Phase 1: recover (h[c], s[c]) from both dense sketch matrices in one launch.
// Blocks 0..511 -> S1 rows, 512..1023 -> S2 rows. All loads issued up-front.
// ---------------------------------------------------------------------------
__global__ __launch_bounds__(256) void extract2(
    const float* __restrict__ S1, const float* __restrict__ S2,
    int* __restrict__ h1, float* __restrict__ s1,
    int* __restrict__ h2, float* __restrict__ s2)
{
    const int  row = blockIdx.x & 511;
    const bool first = blockIdx.x < 512;
    const float* S = first ? S1 : S2;
    int*   h = first ? h1 : h2;
    float* s = first ? s1 : s2;

    const float4* rp = (const float4*)(S + (size_t)row * D);
    float4 v[8];
    #pragma unroll
    for (int ii = 0; ii < 8; ++ii) v[ii] = rp[threadIdx.x + 256 * ii];

    #pragma unroll
    for (int ii = 0; ii < 8; ++ii) {
        const int base = 4 * (threadIdx.x + 256 * ii);
        if (v[ii].x != 0.f) { h[row] = base + 0; s[row] = v[ii].x; }
        if (v[ii].y != 0.f) { h[row] = base + 1; s[row] = v[ii].y; }
        if (v[ii].z != 0.f) { h[row] = base + 2; s[row] = v[ii].z; }
        if (v[ii].w != 0.f) { h[row] = base + 3; s[row] = v[ii].w; }
    }
}

// ---------------------------------------------------------------------------
// Phase 2: bf16-MFMA GEMM (128x128 tile, K=196 padded to 224) + LDS-histogram
// scatter + coalesced global-atomic flush.
// Grid (4 c2-tiles, 4 c1-tiles, 32 batches) = 512 blocks, 256 threads.
// Wave w owns a 64x64 quadrant = 4x4 tiles of 16x16; one MFMA/tile/chunk.
// ---------------------------------------------------------------------------
__global__ __launch_bounds__(256, 2) void cbp_mfma(
    const float* __restrict__ b1, const float* __restrict__ b2,
    const int* __restrict__ h1, const float* __restrict__ s1,
    const int* __restrict__ h2, const float* __restrict__ s2,
    float* __restrict__ out)
{
    const int b  = blockIdx.z;
    const int t1 = blockIdx.y;   // c1 tile base t1*128
    const int t2 = blockIdx.x;   // c2 tile base t2*128

    __shared__ float hist[D];                          // 32 KB
    __shared__ __align__(16) unsigned short As[128 * LDK];  // 10 KB
    __shared__ __align__(16) unsigned short Bs[128 * LDK];  // 10 KB
    __shared__ int h1t[128], h2t[128];

    const int tid = threadIdx.x;

    // zero histogram (2048 float4)
    #pragma unroll
    for (int i = 0; i < 8; ++i) {
        float4 z = {0.f, 0.f, 0.f, 0.f};
        ((float4*)hist)[tid + 256 * i] = z;
    }
    if (tid < 128) {
        h1t[tid] = h1[t1 * 128 + tid];
        h2t[tid] = h2[t2 * 128 + tid];
    }

    // staging mapping: thread covers rows rr+{0,32,64,96}, float4-col kq4/4
    const int rr  = tid >> 3;         // 0..31
    const int kq4 = (tid & 7) * 4;    // 0,4,..,28

    const float* Abase = b1 + ((size_t)b * C + (size_t)t1 * 128) * HW;
    const float* Bbase = b2 + ((size_t)b * C + (size_t)t2 * 128) * HW;

    unsigned am[4], bm[4];
    #pragma unroll
    for (int ii = 0; ii < 4; ++ii) {
        am[ii] = (s1[t1 * 128 + rr + 32 * ii] < 0.f) ? 0x80000000u : 0u;
        bm[ii] = (s2[t2 * 128 + rr + 32 * ii] < 0.f) ? 0x80000000u : 0u;
    }

    // prefetch chunk 0 (k 0..31, always in range: kq4+4 <= 32 <= 196)
    float4 pva[4], pvb[4];
    #pragma unroll
    for (int ii = 0; ii < 4; ++ii) {
        pva[ii] = *(const float4*)(Abase + (size_t)(rr + 32 * ii) * HW + kq4);
        pvb[ii] = *(const float4*)(Bbase + (size_t)(rr + 32 * ii) * HW + kq4);
    }

    // MFMA lane geometry
    const int lane  = tid & 63;
    const int w     = tid >> 6;
    const int ln15  = lane & 15;
    const int qd    = lane >> 4;       // 0..3
    const int koff  = qd * 8;          // k-offset of this lane's 8 bf16
    const int mbase = (w >> 1) * 64;
    const int nbase = (w & 1) * 64;

    f32x4 acc[4][4] = {};

    for (int ch = 0; ch < NCH; ++ch) {
        // store staged registers -> LDS (bf16, sign folded)
        #pragma unroll
        for (int ii = 0; ii < 4; ++ii) {
            const int r = rr + 32 * ii;
            uint2 pa, pb;
            pa.x = (unsigned)f2bf(pva[ii].x, am[ii]) |
                   ((unsigned)f2bf(pva[ii].y, am[ii]) << 16);
            pa.y = (unsigned)f2bf(pva[ii].z, am[ii]) |
                   ((unsigned)f2bf(pva[ii].w, am[ii]) << 16);
            pb.x = (unsigned)f2bf(pvb[ii].x, bm[ii]) |
                   ((unsigned)f2bf(pvb[ii].y, bm[ii]) << 16);
            pb.y = (unsigned)f2bf(pvb[ii].z, bm[ii]) |
                   ((unsigned)f2bf(pvb[ii].w, bm[ii]) << 16);
            *(uint2*)&As[r * LDK + kq4] = pa;
            *(uint2*)&Bs[r * LDK + kq4] = pb;
        }
        __syncthreads();

        // issue next chunk's global loads (in flight across the MFMAs)
        if (ch + 1 < NCH) {
            const int gk = (ch + 1) * 32 + kq4;
            const bool valid = (gk + 4 <= HW);
            const float4 z = {0.f, 0.f, 0.f, 0.f};
            #pragma unroll
            for (int ii = 0; ii < 4; ++ii) {
                pva[ii] = valid ? *(const float4*)(Abase + (size_t)(rr + 32 * ii) * HW + gk) : z;
                pvb[ii] = valid ? *(const float4*)(Bbase + (size_t)(rr + 32 * ii) * HW + gk) : z;
            }
        }

        // fragment reads (conflict-free: stride-80B over 16 lanes) + 16 MFMAs
        bf16x8 av[4], bv[4];
        #pragma unroll
        for (int i = 0; i < 4; ++i)
            av[i] = *(const bf16x8*)&As[(mbase + i * 16 + ln15) * LDK + koff];
        #pragma unroll
        for (int j = 0; j < 4; ++j)
            bv[j] = *(const bf16x8*)&Bs[(nbase + j * 16 + ln15) * LDK + koff];
        #pragma unroll
        for (int i = 0; i < 4; ++i)
            #pragma unroll
            for (int j = 0; j < 4; ++j)
                acc[i][j] = __builtin_amdgcn_mfma_f32_16x16x32_bf16(
                    av[i], bv[j], acc[i][j], 0, 0, 0);
        __syncthreads();
    }

    // scatter: C/D layout col=lane&15, row=(lane>>4)*4+reg  [verified m89/m91]
    int p1v[16];
    #pragma unroll
    for (int i = 0; i < 4; ++i)
        #pragma unroll
        for (int qq = 0; qq < 4; ++qq)
            p1v[i * 4 + qq] = h1t[mbase + i * 16 + qd * 4 + qq];
    int p2v[4];
    #pragma unroll
    for (int j = 0; j < 4; ++j)
        p2v[j] = h2t[nbase + j * 16 + ln15];

    #pragma unroll
    for (int i = 0; i < 4; ++i)
        #pragma unroll
        for (int j = 0; j < 4; ++j)
            #pragma unroll
            for (int qq = 0; qq < 4; ++qq)
                atomicAdd(&hist[(p1v[i * 4 + qq] + p2v[j]) & DMASK], acc[i][j][qq]);

    __syncthreads();

    // flush histogram to global (coalesced, one atomic per element)
    float* orow = out + (size_t)b * D;
    for (int i = tid; i < D; i += 256)
        atomicAdd(&orow[i], hist[i]);
}

// ---------------------------------------------------------------------------
extern "C" void kernel_launch(void* const* d_in, const int* in_sizes, int n_in,
                              void* d_out, int out_size, void* d_ws, size_t ws_size,
                              hipStream_t stream)
{
    const float* bottom1 = (const float*)d_in[0];
    const float* bottom2 = (const float*)d_in[1];
    const float* S1      = (const float*)d_in[2];
    const float* S2      = (const float*)d_in[3];
    float* out = (float*)d_out;

    int*   h1 = (int*)d_ws;
    int*   h2 = h1 + C;
    float* s1 = (float*)(h2 + C);
    float* s2 = s1 + C;

    hipMemsetAsync(d_out, 0, sizeof(float) * NB * D, stream);
    extract2<<<1024, 256, 0, stream>>>(S1, S2, h1, s1, h2, s2);
    cbp_mfma<<<dim3(4, 4, NB), 256, 0, stream>>>(bottom1, bottom2,
                                                 h1, s1, h2, s2, out);
}

// Round 3
// 152.879 us; speedup vs baseline: 1.5225x; 1.0347x over previous
//
#include <hip/hip_runtime.h>

// Compact Bilinear Pooling via count-sketch algebra (no FFT):
//   out[b,d] = sum_{c1,c2 : (h1[c1]+h2[c2]) & 8191 == d} s1[c1]*s2[c2]*G[b,c1,c2]
//   G[b,c1,c2] = sum_{p<196} bottom1[b,c1,p] * bottom2[b,c2,p]
// G via bf16 MFMA (sign +-1 folded exactly at staging); scattered into a
// per-block LDS histogram; flushed with PLAIN float4 stores to a partials
// buffer in d_ws (global atomics were the R2 bottleneck: 4.2M device-scope
// atomics = 88us wall, WRITE_SIZE 16.8MB); reduce kernel sums 16 slices.

#define D     8192
#define DMASK 8191
#define C     512
#define HW    196     // 14*14, contiguous innermost
#define NB    32
#define LDK   40      // bf16/row: 32 data + 8 pad; stride 80B -> conflict-free frag reads
#define NCH   7       // ceil(196/32), tail zero-padded
#define NSL   16      // partial slices per batch (4 t1 x 4 t2)

typedef __attribute__((ext_vector_type(8))) short bf16x8;
typedef __attribute__((ext_vector_type(4))) float f32x4;

// fp32 -> bf16 RNE with sign-mask fold (s = +-1 -> exact xor of sign bit)
__device__ __forceinline__ unsigned short f2bf(float f, unsigned xm) {
    unsigned u = __float_as_uint(f) ^ xm;
    return (unsigned short)((u + 0x7fffu + ((u >> 16) & 1u)) >> 16);
}

// ---------------------------------------------------------------------------
// Phase 1: recover (h[c], s[c]) from both dense sketch matrices in one launch.
// ---------------------------------------------------------------------------
__global__ __launch_bounds__(256) void extract2(
    const float* __restrict__ S1, const float* __restrict__ S2,
    int* __restrict__ h1, float* __restrict__ s1,
    int* __restrict__ h2, float* __restrict__ s2)
{
    const int  row = blockIdx.x & 511;
    const bool first = blockIdx.x < 512;
    const float* S = first ? S1 : S2;
    int*   h = first ? h1 : h2;
    float* s = first ? s1 : s2;

    const float4* rp = (const float4*)(S + (size_t)row * D);
    float4 v[8];
    #pragma unroll
    for (int ii = 0; ii < 8; ++ii) v[ii] = rp[threadIdx.x + 256 * ii];

    #pragma unroll
    for (int ii = 0; ii < 8; ++ii) {
        const int base = 4 * (threadIdx.x + 256 * ii);
        if (v[ii].x != 0.f) { h[row] = base + 0; s[row] = v[ii].x; }
        if (v[ii].y != 0.f) { h[row] = base + 1; s[row] = v[ii].y; }
        if (v[ii].z != 0.f) { h[row] = base + 2; s[row] = v[ii].z; }
        if (v[ii].w != 0.f) { h[row] = base + 3; s[row] = v[ii].w; }
    }
}

// ---------------------------------------------------------------------------
// Phase 2: bf16-MFMA GEMM (128x128 tile, K=196 padded) + LDS-histogram
// scatter + plain-store flush to partials P[b*16 + t1*4 + t2][8192].
// Grid (4 c2-tiles, 4 c1-tiles, 32 batches) = 512 blocks, 256 threads.
// ---------------------------------------------------------------------------
__global__ __launch_bounds__(256, 2) void cbp_mfma(
    const float* __restrict__ b1, const float* __restrict__ b2,
    const int* __restrict__ h1, const float* __restrict__ s1,
    const int* __restrict__ h2, const float* __restrict__ s2,
    float* __restrict__ P)
{
    const int b  = blockIdx.z;
    const int t1 = blockIdx.y;
    const int t2 = blockIdx.x;

    __shared__ float hist[D];                               // 32 KB
    __shared__ __align__(16) unsigned short As[128 * LDK];  // 10 KB
    __shared__ __align__(16) unsigned short Bs[128 * LDK];  // 10 KB
    __shared__ int h1t[128], h2t[128];

    const int tid = threadIdx.x;

    // zero histogram (2048 float4)
    #pragma unroll
    for (int i = 0; i < 8; ++i) {
        float4 z = {0.f, 0.f, 0.f, 0.f};
        ((float4*)hist)[tid + 256 * i] = z;
    }
    if (tid < 128) {
        h1t[tid] = h1[t1 * 128 + tid];
        h2t[tid] = h2[t2 * 128 + tid];
    }

    // staging mapping: thread covers rows rr+{0,32,64,96}, float4-col kq4
    const int rr  = tid >> 3;         // 0..31
    const int kq4 = (tid & 7) * 4;    // 0,4,..,28

    const float* Abase = b1 + ((size_t)b * C + (size_t)t1 * 128) * HW;
    const float* Bbase = b2 + ((size_t)b * C + (size_t)t2 * 128) * HW;

    unsigned am[4], bm[4];
    #pragma unroll
    for (int ii = 0; ii < 4; ++ii) {
        am[ii] = (s1[t1 * 128 + rr + 32 * ii] < 0.f) ? 0x80000000u : 0u;
        bm[ii] = (s2[t2 * 128 + rr + 32 * ii] < 0.f) ? 0x80000000u : 0u;
    }

    // prefetch chunk 0 (k 0..31 always in range)
    float4 pva[4], pvb[4];
    #pragma unroll
    for (int ii = 0; ii < 4; ++ii) {
        pva[ii] = *(const float4*)(Abase + (size_t)(rr + 32 * ii) * HW + kq4);
        pvb[ii] = *(const float4*)(Bbase + (size_t)(rr + 32 * ii) * HW + kq4);
    }

    // MFMA lane geometry
    const int lane  = tid & 63;
    const int w     = tid >> 6;
    const int ln15  = lane & 15;
    const int qd    = lane >> 4;
    const int koff  = qd * 8;
    const int mbase = (w >> 1) * 64;
    const int nbase = (w & 1) * 64;

    f32x4 acc[4][4] = {};

    for (int ch = 0; ch < NCH; ++ch) {
        #pragma unroll
        for (int ii = 0; ii < 4; ++ii) {
            const int r = rr + 32 * ii;
            uint2 pa, pb;
            pa.x = (unsigned)f2bf(pva[ii].x, am[ii]) |
                   ((unsigned)f2bf(pva[ii].y, am[ii]) << 16);
            pa.y = (unsigned)f2bf(pva[ii].z, am[ii]) |
                   ((unsigned)f2bf(pva[ii].w, am[ii]) << 16);
            pb.x = (unsigned)f2bf(pvb[ii].x, bm[ii]) |
                   ((unsigned)f2bf(pvb[ii].y, bm[ii]) << 16);
            pb.y = (unsigned)f2bf(pvb[ii].z, bm[ii]) |
                   ((unsigned)f2bf(pvb[ii].w, bm[ii]) << 16);
            *(uint2*)&As[r * LDK + kq4] = pa;
            *(uint2*)&Bs[r * LDK + kq4] = pb;
        }
        __syncthreads();

        if (ch + 1 < NCH) {
            const int gk = (ch + 1) * 32 + kq4;
            const bool valid = (gk + 4 <= HW);
            const float4 z = {0.f, 0.f, 0.f, 0.f};
            #pragma unroll
            for (int ii = 0; ii < 4; ++ii) {
                pva[ii] = valid ? *(const float4*)(Abase + (size_t)(rr + 32 * ii) * HW + gk) : z;
                pvb[ii] = valid ? *(const float4*)(Bbase + (size_t)(rr + 32 * ii) * HW + gk) : z;
            }
        }

        bf16x8 av[4], bv[4];
        #pragma unroll
        for (int i = 0; i < 4; ++i)
            av[i] = *(const bf16x8*)&As[(mbase + i * 16 + ln15) * LDK + koff];
        #pragma unroll
        for (int j = 0; j < 4; ++j)
            bv[j] = *(const bf16x8*)&Bs[(nbase + j * 16 + ln15) * LDK + koff];
        #pragma unroll
        for (int i = 0; i < 4; ++i)
            #pragma unroll
            for (int j = 0; j < 4; ++j)
                acc[i][j] = __builtin_amdgcn_mfma_f32_16x16x32_bf16(
                    av[i], bv[j], acc[i][j], 0, 0, 0);
        __syncthreads();
    }

    // scatter: C/D layout col=lane&15, row=(lane>>4)*4+reg  [m89/m91]
    int p1v[16];
    #pragma unroll
    for (int i = 0; i < 4; ++i)
        #pragma unroll
        for (int qq = 0; qq < 4; ++qq)
            p1v[i * 4 + qq] = h1t[mbase + i * 16 + qd * 4 + qq];
    int p2v[4];
    #pragma unroll
    for (int j = 0; j < 4; ++j)
        p2v[j] = h2t[nbase + j * 16 + ln15];

    #pragma unroll
    for (int i = 0; i < 4; ++i)
        #pragma unroll
        for (int j = 0; j < 4; ++j)
            #pragma unroll
            for (int qq = 0; qq < 4; ++qq)
                atomicAdd(&hist[(p1v[i * 4 + qq] + p2v[j]) & DMASK], acc[i][j][qq]);

    __syncthreads();

    // flush: PLAIN coalesced float4 stores to this block's partial slice
    float* Pslice = P + ((size_t)(b * NSL + t1 * 4 + t2)) * D;
    #pragma unroll
    for (int i = 0; i < 8; ++i)
        ((float4*)Pslice)[tid + 256 * i] = ((const float4*)hist)[tid + 256 * i];
}

// ---------------------------------------------------------------------------
// Phase 3: out[b,d] = sum over 16 slices of P. 256 blocks x 256 threads,
// one float4 of output per thread; 16 coalesced float4 loads each.
// ---------------------------------------------------------------------------
__global__ __launch_bounds__(256) void reduce16(
    const float* __restrict__ P, float* __restrict__ out)
{
    const int idx4 = blockIdx.x * 256 + threadIdx.x;   // 0..65535
    const int b    = idx4 >> 11;                       // /2048 float4s per row
    const int d4   = idx4 & 2047;

    const float4* base = (const float4*)(P + (size_t)b * NSL * D) + d4;
    float4 v[NSL];
    #pragma unroll
    for (int s = 0; s < NSL; ++s) v[s] = base[s * (D / 4)];

    float4 acc = v[0];
    #pragma unroll
    for (int s = 1; s < NSL; ++s) {
        acc.x += v[s].x; acc.y += v[s].y; acc.z += v[s].z; acc.w += v[s].w;
    }
    ((float4*)out)[idx4] = acc;
}

// ---------------------------------------------------------------------------
extern "C" void kernel_launch(void* const* d_in, const int* in_sizes, int n_in,
                              void* d_out, int out_size, void* d_ws, size_t ws_size,
                              hipStream_t stream)
{
    const float* bottom1 = (const float*)d_in[0];
    const float* bottom2 = (const float*)d_in[1];
    const float* S1      = (const float*)d_in[2];
    const float* S2      = (const float*)d_in[3];
    float* out = (float*)d_out;

    float* P  = (float*)d_ws;                 // 512 * 8192 floats = 16 MB
    int*   h1 = (int*)(P + (size_t)NB * NSL * D);
    int*   h2 = h1 + C;
    float* s1 = (float*)(h2 + C);
    float* s2 = s1 + C;

    extract2<<<1024, 256, 0, stream>>>(S1, S2, h1, s1, h2, s2);
    cbp_mfma<<<dim3(4, 4, NB), 256, 0, stream>>>(bottom1, bottom2,
                                                 h1, s1, h2, s2, P);
    reduce16<<<256, 256, 0, stream>>>(P, out);
}